// Round 16
// baseline (1576.844 us; speedup 1.0000x reference)
//
#include <hip/hip_runtime.h>

#define H 181
#define T_LEN 1024
#define BB 2             // batch rows per block
#define NBLK 512         // 512 * 2 = 1024; TWO blocks per CU (indep. barriers)
#define NTHR 384         // 6 waves
#define KT3 3            // k-tiles of 64 -> 192 >= 181
#define FRAGB 1024       // bytes per kt fragment (64 lanes x 16 B)
#define PST 192          // unit stride (wsc, FC)
#define XSTR 1027        // x_s stride (odd -> broadcast reads conflict-free)

typedef __attribute__((ext_vector_type(4))) int intx4;

#define LOG2E 1.4426950408889634f
// Schraudolph exp2 (balanced sawtooth, |rel err| <= ~3%), clamped to [-20,14]
#define SCH_C  1064992506.0f
#define SCH_LO 897220352.0f
#define SCH_HI 1182433024.0f

__device__ __forceinline__ float exp2_fast(float g) {
    float s = fmaf(g, 8388608.0f, SCH_C);
    s = fminf(fmaxf(s, SCH_LO), SCH_HI);
    return __uint_as_float((unsigned)s);
}
__device__ __forceinline__ float rcpf(float x)   { return __builtin_amdgcn_rcpf(x); }
__device__ __forceinline__ float exp2hw(float x) { return __builtin_amdgcn_exp2f(x); }

// 512 blocks x 2 batch, 6 waves, TWO independent barrier domains per CU
// (R15 idea; R15 itself spilled afr to scratch: WRITE_SIZE 140 MB, cap 170
// at launch_bounds(.,3), peak pressure from 2-step unroll + 6 live acc
// chains). R16 fixes pressure, not the structure:
//  - gates processed SEQUENTIALLY: per gate 6 MFMAs -> DPP redistribute ->
//    one reg; 8 acc regs reused across gates (was 24 live).
//  - NO 2-step unroll: single body, runtime rb/wb pointer swap.
// Everything else identical to R15 (DPP maps validated by R15's correct
// absmax): lane = q*16 + r*4 + tau*2 + b <- reg r, col b, tile tau.
__launch_bounds__(NTHR, 3)
__global__ void gru_i8(const float* __restrict__ x,
                       const float* __restrict__ w_ih,
                       const float* __restrict__ w_hh,
                       const float* __restrict__ b_ih,
                       const float* __restrict__ b_hh,
                       const float* __restrict__ w_fc,
                       const float* __restrict__ b_fc,
                       float* __restrict__ out) {
    __shared__ __align__(16) char  hfr_s[2 * KT3 * FRAGB];  // 6 KB i8 h dbuf
    __shared__ __align__(16) float x_s[BB * XSTR];          // 8.2 KB x; reused for FC
    __shared__ float wsc_s[3 * PST];                        // w_hh row scales

    const int tid  = threadIdx.x;
    const int jt   = tid >> 6;          // wave 0..5: unit tiles {2jt, 2jt+1}
    const int lane = tid & 63;
    const int col  = lane & 15;
    const int q    = lane >> 4;
    const int b0   = blockIdx.x * BB;

    // ---- A fragments: per-row int8 w_hh, [tau][gate][kt] ----
    intx4 afr[2][3][KT3];
    #pragma unroll
    for (int tt = 0; tt < 2; ++tt) {
        const int  mu = (2 * jt + tt) * 16 + col;
        const bool mv = (mu < H);
        #pragma unroll
        for (int g = 0; g < 3; ++g) {
            const float* wrow = w_hh + (size_t)(g * H + (mv ? mu : 0)) * H;
            float rm = 0.0f;
            if (mv) for (int k = 0; k < H; ++k) rm = fmaxf(rm, fabsf(wrow[k]));
            float s    = (rm > 1e-30f) ? rm * (1.0f / 127.0f) : 1.0f;
            float invs = 1.0f / s;
            #pragma unroll
            for (int kt = 0; kt < KT3; ++kt) {
                union { signed char c[16]; intx4 v; } uu;
                #pragma unroll
                for (int e = 0; e < 16; ++e) {
                    int k = kt * 64 + q * 16 + e;
                    float v = (mv && k < H) ? wrow[k] * invs : 0.0f;
                    v = fminf(fmaxf(rintf(v), -127.0f), 127.0f);
                    uu.c[e] = (signed char)(int)v;
                }
                afr[tt][g][kt] = uu.v;
            }
            if (q == 0) wsc_s[g * PST + mu] = s;
        }
    }

    // ---- stage x (stride 1027); zero h frag buffers ----
    for (int i = tid; i < BB * T_LEN; i += NTHR) {
        int bb = i >> 10, t = i & 1023;
        x_s[bb * XSTR + t] = x[(size_t)b0 * T_LEN + i];
    }
    {
        int* hz = (int*)hfr_s;
        for (int i = tid; i < 2 * KT3 * FRAGB / 4; i += NTHR) hz[i] = 0;
    }
    __syncthreads();   // wsc_s ready

    // ---- dense per-lane identity: lane = q*16 + r*4 + tau*2 + b ----
    const int  rr4 = (lane >> 2) & 3;           // reg index r
    const int  tau = (lane >> 1) & 1;           // tile half
    const int  b   = lane & 1;                  // batch
    const int  u   = (2 * jt + tau) * 16 + q * 4 + rr4;   // unit 0..191
    const bool jv  = (u < H);
    const float dqR = -LOG2E * wsc_s[0 * PST + u] * (1.0f / 127.0f);
    const float dqZ = -LOG2E * wsc_s[1 * PST + u] * (1.0f / 127.0f);
    const float dqN =  2.0f * LOG2E * wsc_s[2 * PST + u] * (1.0f / 127.0f);
    const float baseR = jv ? -LOG2E * (b_ih[u] + b_hh[u])             : 0.0f;
    const float baseZ = jv ? -LOG2E * (b_ih[H + u] + b_hh[H + u])     : 0.0f;
    const float baseN = jv ?  2.0f * LOG2E * b_hh[2 * H + u]          : 0.0f;
    const float wrS = jv ? -LOG2E * w_ih[u]                : 0.0f;
    const float wzS = jv ? -LOG2E * w_ih[H + u]            : 0.0f;
    const float wnS = jv ?  2.0f * LOG2E * w_ih[2 * H + u] : 0.0f;
    const float bnI = jv ?  2.0f * LOG2E * b_ih[2 * H + u] : 0.0f;
    // leader (r==0) packs units u0..u0+3 (fixed tau,b) and writes one b32
    const int u0    = (2 * jt + tau) * 16 + q * 4;
    const int woffB = (u0 >> 6) * FRAGB + (((u0 >> 4) & 3) * 16 + b) * 16 + (u0 & 15);
    const int rbase = lane * 16;

    float h = 0.0f;

    char* rb = hfr_s;
    char* wb = hfr_s + KT3 * FRAGB;

    for (int t = 0; t < T_LEN; ++t) {
        intx4 bf[KT3];
        #pragma unroll
        for (int kt = 0; kt < KT3; ++kt)
            bf[kt] = *(const intx4*)(rb + kt * FRAGB + rbase);

        // ---- sequential gates: 6 MFMAs -> DPP redistribute -> one reg ----
        int v3[3];
        #pragma unroll
        for (int g = 0; g < 3; ++g) {
            intx4 a0 = {0, 0, 0, 0}, a1 = {0, 0, 0, 0};
            #pragma unroll
            for (int kt = 0; kt < KT3; ++kt) {
                a0 = __builtin_amdgcn_mfma_i32_16x16x64_i8(afr[0][g][kt], bf[kt], a0, 0, 0, 0);
                a1 = __builtin_amdgcn_mfma_i32_16x16x64_i8(afr[1][g][kt], bf[kt], a1, 0, 0, 0);
            }
            int v = a0[0];                                                  // tau0 r0: lanes +0,+1
            v = __builtin_amdgcn_update_dpp(v, a0[1], 0x114, 0xF, 0x2, false); // tau0 r1 shr4
            v = __builtin_amdgcn_update_dpp(v, a0[2], 0x118, 0xF, 0x4, false); // tau0 r2 shr8
            v = __builtin_amdgcn_update_dpp(v, a0[3], 0x11C, 0xF, 0x8, false); // tau0 r3 shr12
            v = __builtin_amdgcn_update_dpp(v, a1[0], 0x112, 0xF, 0x1, false); // tau1 r0 shr2
            v = __builtin_amdgcn_update_dpp(v, a1[1], 0x116, 0xF, 0x2, false); // tau1 r1 shr6
            v = __builtin_amdgcn_update_dpp(v, a1[2], 0x11A, 0xF, 0x4, false); // tau1 r2 shr10
            v = __builtin_amdgcn_update_dpp(v, a1[3], 0x11E, 0xF, 0x8, false); // tau1 r3 shr14
            v3[g] = v;
        }

        // ---- dense dequant + gates (R14/R15 numerics, bit-identical) ----
        float pR = fmaf((float)v3[0], dqR, baseR);
        float pZ = fmaf((float)v3[1], dqZ, baseZ);
        float pN = fmaf((float)v3[2], dqN, baseN);
        float xv = x_s[b * XSTR + t];

        float er = exp2_fast(fmaf(xv, wrS, pR));
        float ez = exp2hw(fminf(fmaf(xv, wzS, pZ), 14.0f));
        float dR = 1.0f + er, dZ = 1.0f + ez;
        float qq = rcpf(dR * dZ);
        float rr = qq * dZ, zz = qq * dR;
        float gn = fmaf(rr, pN, fmaf(xv, wnS, bnI));
        float en = exp2hw(fminf(gn, 30.0f));
        float nn = fmaf(-2.0f, rcpf(1.0f + en), 1.0f);  // tanh
        h = fmaf(zz, h - nn, nn);                        // |h|<1

        int iq = (int)rintf(h * 127.0f);
        int hq = jv ? (iq & 255) : 0;
        // ---- DPP gather (row_shl:4/8/12) + perm pack: bytes r=0..3 ----
        int t1 = __builtin_amdgcn_update_dpp(0, hq, 0x104, 0xF, 0xF, true);
        int t2 = __builtin_amdgcn_update_dpp(0, hq, 0x108, 0xF, 0xF, true);
        int t3 = __builtin_amdgcn_update_dpp(0, hq, 0x10C, 0xF, 0xF, true);
        int p01 = __builtin_amdgcn_perm(t1, hq, 0x05010400);
        int p23 = __builtin_amdgcn_perm(t3, t2, 0x05010400);
        int pk  = __builtin_amdgcn_perm(p23, p01, 0x05040100);
        if (rr4 == 0)
            *(int*)(wb + woffB) = pk;
        __syncthreads();   // the only barrier per step (per block)

        char* tmp = rb; rb = wb; wb = tmp;
    }

    // ---- final FC: publish h (f32) into x_s (x done), 20 lanes reduce ----
    __syncthreads();
    x_s[b * PST + u] = h;    // u < 192; pads hold garbage, FC reads k < H only
    __syncthreads();
    if (tid < BB * 10) {
        int bb = tid / 10, c = tid % 10;
        float acc = b_fc[c];
        for (int k = 0; k < H; ++k)
            acc = fmaf(x_s[bb * PST + k], w_fc[c * H + k], acc);
        out[(b0 + bb) * 10 + c] = acc;
    }
}

extern "C" void kernel_launch(void* const* d_in, const int* in_sizes, int n_in,
                              void* d_out, int out_size, void* d_ws, size_t ws_size,
                              hipStream_t stream) {
    const float* x    = (const float*)d_in[0];
    const float* w_ih = (const float*)d_in[1];
    const float* w_hh = (const float*)d_in[2];
    const float* b_ih = (const float*)d_in[3];
    const float* b_hh = (const float*)d_in[4];
    const float* w_fc = (const float*)d_in[5];
    const float* b_fc = (const float*)d_in[6];
    float* out = (float*)d_out;

    gru_i8<<<NBLK, NTHR, 0, stream>>>(x, w_ih, w_hh, b_ih, b_hh, w_fc, b_fc, out);
}

// Round 17
// 709.414 us; speedup vs baseline: 2.2227x; 2.2227x over previous
//
#include <hip/hip_runtime.h>

#define H 181
#define T_LEN 1024
#define BB 4             // batch rows per block
#define NBLK 256         // 256 * 4 = 1024; one block per CU (LDS-pinned)
#define NTHR 768         // 12 waves, 3 per SIMD
#define KT3 3            // k-tiles of 64 -> 192 >= 181
#define FRAGB 1024       // bytes per kt fragment (64 lanes x 16 B)
#define PST 192          // unit stride (wsc, FC)
#define XSTR 1027        // x_s stride (odd -> broadcast reads conflict-free)

typedef __attribute__((ext_vector_type(4))) int intx4;

#define LOG2E 1.4426950408889634f
// Schraudolph exp2 (balanced sawtooth, |rel err| <= ~3%), clamped to [-20,14]
#define SCH_C  1064992506.0f
#define SCH_LO 897220352.0f
#define SCH_HI 1182433024.0f

__device__ __forceinline__ float exp2_fast(float g) {
    float s = fmaf(g, 8388608.0f, SCH_C);
    s = fminf(fmaxf(s, SCH_LO), SCH_HI);
    return __uint_as_float((unsigned)s);
}
__device__ __forceinline__ float rcpf(float x)   { return __builtin_amdgcn_rcpf(x); }
__device__ __forceinline__ float exp2hw(float x) { return __builtin_amdgcn_exp2f(x); }

// R14 structure (best: 715 us), ONE change: A-fragments are built with pure
// register arithmetic (byte pack via and/shift/or), NOT through a char-array
// union. The union defeated SROA in R11-R16: afr lived in SCRATCH (VGPR_Count
// stuck at 84; WRITE_SIZE 26-139 MB = scratch write-back), and every t-step
// reloaded ~110 KB/CU of A-frags through buffer_load - the suspected true
// identity of the ~835 cy/step "idle". With SROA, afr = 36 VGPRs (fits: cap
// ~170 at 3 waves/SIMD).
// Structure: 256 blocks x 4 batch, 12 waves, wave jt owns unit-tile jt for
// all 3 gates (9 mfma_i32_16x16x64_i8/step); DPP redistribute to dense
// per-lane (unit,batch) triples; gates r=Schraudolph, z/n=exact exp;
// DPP gather + perm pack; leader b32 write; ONE barrier per step.
__launch_bounds__(NTHR, 3)
__global__ void gru_i8(const float* __restrict__ x,
                       const float* __restrict__ w_ih,
                       const float* __restrict__ w_hh,
                       const float* __restrict__ b_ih,
                       const float* __restrict__ b_hh,
                       const float* __restrict__ w_fc,
                       const float* __restrict__ b_fc,
                       float* __restrict__ out) {
    __shared__ __align__(16) char  hfr_s[2 * KT3 * FRAGB];  // 6 KB i8 h dbuf
    __shared__ __align__(16) float x_s[BB * XSTR];          // 16 KB x; reused for FC
    __shared__ float wsc_s[3 * PST];                        // w_hh row scales
    __shared__ volatile char pad_s[57344];                  // total > 80 KB: pin 1 block/CU

    const int tid  = threadIdx.x;
    const int jt   = tid >> 6;          // wave = unit tile 0..11
    const int lane = tid & 63;
    const int col  = lane & 15;
    const int q    = lane >> 4;
    const int b0   = blockIdx.x * BB;
    if (tid == 0) pad_s[0] = 0;

    // ---- A fragments: per-row int8 w_hh, 3 gates x 3 kt (m = jt*16+col) ----
    // Built entirely in registers: dword = b0 | b1<<8 | b2<<16 | b3<<24.
    const int  mu = jt * 16 + col;
    const bool mv = (mu < H);
    intx4 afr[3][KT3];
    #pragma unroll
    for (int g = 0; g < 3; ++g) {
        const float* wrow = w_hh + (size_t)(g * H + (mv ? mu : 0)) * H;
        float rm = 0.0f;
        if (mv) for (int k = 0; k < H; ++k) rm = fmaxf(rm, fabsf(wrow[k]));
        float s    = (rm > 1e-30f) ? rm * (1.0f / 127.0f) : 1.0f;
        float invs = 1.0f / s;
        #pragma unroll
        for (int kt = 0; kt < KT3; ++kt) {
            intx4 frag;
            #pragma unroll
            for (int w = 0; w < 4; ++w) {
                int dw = 0;
                #pragma unroll
                for (int e = 0; e < 4; ++e) {
                    int k = kt * 64 + q * 16 + w * 4 + e;
                    float v = (mv && k < H) ? wrow[k] * invs : 0.0f;
                    v = fminf(fmaxf(rintf(v), -127.0f), 127.0f);
                    int iv = (int)v;
                    dw |= (iv & 255) << (8 * e);
                }
                frag[w] = dw;
            }
            afr[g][kt] = frag;
        }
        if (q == 0) wsc_s[g * PST + mu] = s;
    }

    // ---- stage x (stride 1027); zero h frag buffers ----
    for (int i = tid; i < BB * T_LEN; i += NTHR) {
        int bb = i >> 10, t = i & 1023;
        x_s[bb * XSTR + t] = x[(size_t)b0 * T_LEN + i];
    }
    {
        int* hz = (int*)hfr_s;
        for (int i = tid; i < 2 * KT3 * FRAGB / 4; i += NTHR) hz[i] = 0;
    }
    __syncthreads();   // wsc_s ready

    // ---- dense per-lane identity after DPP redistribute ----
    const int  rr4 = (col >> 2) & 3;       // reg index this lane receives
    const int  b   = col & 3;              // batch
    const int  u   = jt * 16 + q * 4 + rr4;  // unit
    const bool jv  = (u < H);
    const float dqR = -LOG2E * wsc_s[0 * PST + u] * (1.0f / 127.0f);
    const float dqZ = -LOG2E * wsc_s[1 * PST + u] * (1.0f / 127.0f);
    const float dqN =  2.0f * LOG2E * wsc_s[2 * PST + u] * (1.0f / 127.0f);
    const float baseR = jv ? -LOG2E * (b_ih[u] + b_hh[u])             : 0.0f;
    const float baseZ = jv ? -LOG2E * (b_ih[H + u] + b_hh[H + u])     : 0.0f;
    const float baseN = jv ?  2.0f * LOG2E * b_hh[2 * H + u]          : 0.0f;
    const float wrS = jv ? -LOG2E * w_ih[u]                : 0.0f;
    const float wzS = jv ? -LOG2E * w_ih[H + u]            : 0.0f;
    const float wnS = jv ?  2.0f * LOG2E * w_ih[2 * H + u] : 0.0f;
    const float bnI = jv ?  2.0f * LOG2E * b_ih[2 * H + u] : 0.0f;
    // leader (rr4==0) packs 4 units' bytes and writes one b32
    const int woffB = (jt >> 2) * FRAGB + (((jt & 3) * 16 + b) * 16) + q * 4;
    const int rbase = lane * 16;

    float h = 0.0f;

    auto step = [&](const char* rb, char* wb, int t) {
        intx4 bf[KT3];
        #pragma unroll
        for (int kt = 0; kt < KT3; ++kt)
            bf[kt] = *(const intx4*)(rb + kt * FRAGB + rbase);
        intx4 aR = {0,0,0,0}, aZ = {0,0,0,0}, aN = {0,0,0,0};
        #pragma unroll
        for (int kt = 0; kt < KT3; ++kt) {
            aR = __builtin_amdgcn_mfma_i32_16x16x64_i8(afr[0][kt], bf[kt], aR, 0, 0, 0);
            aZ = __builtin_amdgcn_mfma_i32_16x16x64_i8(afr[1][kt], bf[kt], aZ, 0, 0, 0);
            aN = __builtin_amdgcn_mfma_i32_16x16x64_i8(afr[2][kt], bf[kt], aN, 0, 0, 0);
        }

        // ---- DPP redistribute: lane q*16+r*4+b <- reg r of lane q*16+b ----
        int vR = aR[0], vZ = aZ[0], vN = aN[0];
        vR = __builtin_amdgcn_update_dpp(vR, aR[1], 0x114, 0xF, 0x2, false);
        vR = __builtin_amdgcn_update_dpp(vR, aR[2], 0x118, 0xF, 0x4, false);
        vR = __builtin_amdgcn_update_dpp(vR, aR[3], 0x11C, 0xF, 0x8, false);
        vZ = __builtin_amdgcn_update_dpp(vZ, aZ[1], 0x114, 0xF, 0x2, false);
        vZ = __builtin_amdgcn_update_dpp(vZ, aZ[2], 0x118, 0xF, 0x4, false);
        vZ = __builtin_amdgcn_update_dpp(vZ, aZ[3], 0x11C, 0xF, 0x8, false);
        vN = __builtin_amdgcn_update_dpp(vN, aN[1], 0x114, 0xF, 0x2, false);
        vN = __builtin_amdgcn_update_dpp(vN, aN[2], 0x118, 0xF, 0x4, false);
        vN = __builtin_amdgcn_update_dpp(vN, aN[3], 0x11C, 0xF, 0x8, false);

        // ---- dense dequant + gates (R14 numerics, bit-identical) ----
        float pR = fmaf((float)vR, dqR, baseR);
        float pZ = fmaf((float)vZ, dqZ, baseZ);
        float pN = fmaf((float)vN, dqN, baseN);
        float xv = x_s[b * XSTR + t];

        float er = exp2_fast(fmaf(xv, wrS, pR));
        float ez = exp2hw(fminf(fmaf(xv, wzS, pZ), 14.0f));
        float dR = 1.0f + er, dZ = 1.0f + ez;
        float qq = rcpf(dR * dZ);
        float rr = qq * dZ, zz = qq * dR;
        float gn = fmaf(rr, pN, fmaf(xv, wnS, bnI));
        float en = exp2hw(fminf(gn, 30.0f));
        float nn = fmaf(-2.0f, rcpf(1.0f + en), 1.0f);  // tanh
        h = fmaf(zz, h - nn, nn);                        // |h|<1

        int iq = (int)rintf(h * 127.0f);
        int hq = jv ? (iq & 255) : 0;
        // ---- DPP gather (row_shl:4/8/12) + perm pack: bytes r=0..3 ----
        int t1 = __builtin_amdgcn_update_dpp(0, hq, 0x104, 0xF, 0xF, true);
        int t2 = __builtin_amdgcn_update_dpp(0, hq, 0x108, 0xF, 0xF, true);
        int t3 = __builtin_amdgcn_update_dpp(0, hq, 0x10C, 0xF, 0xF, true);
        int p01 = __builtin_amdgcn_perm(t1, hq, 0x05010400);
        int p23 = __builtin_amdgcn_perm(t3, t2, 0x05010400);
        int pk  = __builtin_amdgcn_perm(p23, p01, 0x05040100);
        if (rr4 == 0)
            *(int*)(wb + woffB) = pk;
        __syncthreads();   // the only barrier per step
    };

    char* buf0 = hfr_s;
    char* buf1 = hfr_s + KT3 * FRAGB;
    for (int t = 0; t < T_LEN; t += 2) {
        step(buf0, buf1, t);
        step(buf1, buf0, t + 1);
    }

    // ---- final FC: publish h (f32) into x_s (x done), 40 lanes reduce ----
    __syncthreads();
    if (u < PST) x_s[b * PST + u] = h;
    __syncthreads();
    if (tid < BB * 10) {
        int bb = tid / 10, c = tid % 10;
        float acc = b_fc[c];
        for (int k = 0; k < H; ++k)
            acc = fmaf(x_s[bb * PST + k], w_fc[c * H + k], acc);
        out[(b0 + bb) * 10 + c] = acc;
    }
}

extern "C" void kernel_launch(void* const* d_in, const int* in_sizes, int n_in,
                              void* d_out, int out_size, void* d_ws, size_t ws_size,
                              hipStream_t stream) {
    const float* x    = (const float*)d_in[0];
    const float* w_ih = (const float*)d_in[1];
    const float* w_hh = (const float*)d_in[2];
    const float* b_ih = (const float*)d_in[3];
    const float* b_hh = (const float*)d_in[4];
    const float* w_fc = (const float*)d_in[5];
    const float* b_fc = (const float*)d_in[6];
    float* out = (float*)d_out;

    gru_i8<<<NBLK, NTHR, 0, stream>>>(x, w_ih, w_hh, b_ih, b_hh, w_fc, b_fc, out);
}